// Round 4
// baseline (135.506 us; speedup 1.0000x reference)
//
#include <hip/hip_runtime.h>

// CrumbReconstructor: for each 8-float block of x, find nearest codebook row
// (squared Euclidean over 256 rows of length 8), output that row.
//
// R4: R3 post-mortem showed the kernel is LDS-PIPE-THROUGHPUT bound, not
// VALU/latency bound: per row per wave, 2x ds_read_b128 + ds_read_b32 ~= 30
// LDS-cyc on the single per-CU LDS pipe; at TPK=2 that's 78us (matches 70us
// measured) vs a 34us VALU floor. Fix: amortize the row read over more keys.
//   802816 keys = 1792 blocks x 64 threads x 7 keys  (EXACT)
// -> TPK=7, block=64 (1 wave), grid=1792 = exactly 7 blocks/CU, no imbalance.
// Per row/wave: 91 VALU instr (182 SIMD-cyc) vs 30 LDS-cyc -> VALU-bound.
// Hot-loop math bit-identical to R0/R3 (absmax 0.0).

#define LBLK 8      // memblock length
#define NROW 256    // codebook rows
#define TPK 7       // key-blocks per thread
#define BLOCK 64    // threads per workgroup (1 wave)

__global__ __launch_bounds__(BLOCK) void crumb_kernel(
    const float* __restrict__ x,
    const float* __restrict__ mem,
    float* __restrict__ out,
    int nblocks,
    int total_threads)
{
    __shared__ float s_mem[NROW * LBLK];   // 8 KB, rows contiguous
    __shared__ float s_norm[NROW];         // 1 KB

    const int tid = threadIdx.x;

    // --- stage codebook: 64 threads x 4 rows each ---
    {
        const float4* g = (const float4*)mem;
        #pragma unroll
        for (int r = 0; r < NROW / BLOCK; ++r) {
            int row = tid + r * BLOCK;
            float4 a = g[row * 2 + 0];
            float4 b = g[row * 2 + 1];
            ((float4*)s_mem)[row * 2 + 0] = a;
            ((float4*)s_mem)[row * 2 + 1] = b;
            // numpy order: elementwise square, 8-wide pairwise tree sum
            float q0 = a.x * a.x, q1 = a.y * a.y, q2 = a.z * a.z, q3 = a.w * a.w;
            float q4 = b.x * b.x, q5 = b.y * b.y, q6 = b.z * b.z, q7 = b.w * b.w;
            s_norm[row] = ((q0 + q1) + (q2 + q3)) + ((q4 + q5) + (q6 + q7));
        }
    }
    __syncthreads();

    const int g0 = blockIdx.x * BLOCK + tid;   // first key for this thread

    float k[TPK][LBLK];
    float knorm[TPK];
    long  kb[TPK];
    bool  valid[TPK];

    #pragma unroll
    for (int t = 0; t < TPK; ++t) {
        long b0 = (long)g0 + (long)t * total_threads;   // strided -> coalesced
        valid[t] = (b0 < (long)nblocks);
        kb[t] = valid[t] ? b0 : 0;
        const float4* g = (const float4*)(x + kb[t] * LBLK);
        float4 a = g[0], b = g[1];
        k[t][0] = a.x; k[t][1] = a.y; k[t][2] = a.z; k[t][3] = a.w;
        k[t][4] = b.x; k[t][5] = b.y; k[t][6] = b.z; k[t][7] = b.w;
        float q0 = a.x * a.x, q1 = a.y * a.y, q2 = a.z * a.z, q3 = a.w * a.w;
        float q4 = b.x * b.x, q5 = b.y * b.y, q6 = b.z * b.z, q7 = b.w * b.w;
        knorm[t] = ((q0 + q1) + (q2 + q3)) + ((q4 + q5) + (q6 + q7));
    }

    float best[TPK];
    int   bidx[TPK];
    #pragma unroll
    for (int t = 0; t < TPK; ++t) { best[t] = 3.4e38f; bidx[t] = 0; }

    // --- score all 256 rows; one row read amortized over 7 keys ---
    #pragma unroll 2
    for (int m = 0; m < NROW; ++m) {
        float4 a = ((const float4*)s_mem)[m * 2 + 0];
        float4 b = ((const float4*)s_mem)[m * 2 + 1];
        float nrm = s_norm[m];

        #pragma unroll
        for (int t = 0; t < TPK; ++t) {
            // sequential FMA dot, bit-identical to R0/R3 (absmax 0)
            float dot = k[t][0] * a.x;
            dot = fmaf(k[t][1], a.y, dot);
            dot = fmaf(k[t][2], a.z, dot);
            dot = fmaf(k[t][3], a.w, dot);
            dot = fmaf(k[t][4], b.x, dot);
            dot = fmaf(k[t][5], b.y, dot);
            dot = fmaf(k[t][6], b.z, dot);
            dot = fmaf(k[t][7], b.w, dot);
            float d = fmaf(dot, -2.0f, knorm[t]) + nrm;
            // strict < : first (lowest) index wins exact ties, matches argmin
            if (d < best[t]) { best[t] = d; bidx[t] = m; }
        }
    }

    // --- gather winning rows from LDS, store ---
    #pragma unroll
    for (int t = 0; t < TPK; ++t) {
        if (valid[t]) {
            float4* o = (float4*)(out + kb[t] * LBLK);
            o[0] = ((const float4*)s_mem)[bidx[t] * 2 + 0];
            o[1] = ((const float4*)s_mem)[bidx[t] * 2 + 1];
        }
    }
}

extern "C" void kernel_launch(void* const* d_in, const int* in_sizes, int n_in,
                              void* d_out, int out_size, void* d_ws, size_t ws_size,
                              hipStream_t stream) {
    const float* x   = (const float*)d_in[0];
    const float* mem = (const float*)d_in[1];
    float* out = (float*)d_out;

    int n = in_sizes[0];            // total x elements
    int nblocks = n / LBLK;         // key-blocks (802816)
    int grid = (nblocks + BLOCK * TPK - 1) / (BLOCK * TPK);   // 1792 exact
    int total_threads = grid * BLOCK;

    hipLaunchKernelGGL(crumb_kernel, dim3(grid), dim3(BLOCK), 0, stream,
                       x, mem, out, nblocks, total_threads);
}